// Round 2
// baseline (210.489 us; speedup 1.0000x reference)
//
#include <hip/hip_runtime.h>

// IndependentMLP: x(4096,1024), w0(1024,1,16), w1(1024,16,16), wf(1024,16,8)
// out[b,i,j] = sum_k tanh( sum_l tanh(x[b,i]*w0[i,l]) * w1[i,l,k] ) * wf[i,k,j]
//
// Single fused kernel, no LDS, no barriers, no workspace.
// Per-i tiny GEMMs on v_mfma_f32_16x16x16f16, computed TRANSPOSED so MFMA1's
// C/D layout == MFMA2's B layout (no shuffle between layers):
//   MFMA1: A = w1^T frag, B = h1^T frag  -> D1[n=h2idx][m=batch]
//   MFMA2: A = wf^T frag, B = tanh(D1)   -> D2[j=outcol][m=batch]
// D2 reg ii (g<2) = out[b0+r][i*8 + g*4 + ii] -> one aligned float4 store/lane.
// Waves wid=0..3 (adjacent i) fill adjacent 32B chunks, so L2 write-combines
// full 64B lines before HBM.
//
// x read: lane r reads x[b0+r][i] (4B, 4KB stride). 4 waves of a block share
// each 16B chunk; 4 adjacent-ig blocks share each 64B line -> L2 absorbs most
// of the line amplification. Cheaper than a transpose round-trip.

typedef _Float16 half4 __attribute__((ext_vector_type(4)));
typedef float f32x4 __attribute__((ext_vector_type(4)));

__device__ __forceinline__ float fast_tanh(float x) {
  // tanh(x) = 1 - 2/(exp2(2x*log2e)+1); +-inf/0 endpoints correct.
  float e = __builtin_amdgcn_exp2f(x * 2.885390081777927f);
  return 1.0f - 2.0f * __builtin_amdgcn_rcpf(e + 1.0f);
}

__global__ __launch_bounds__(256) void mlp_fused(const float* __restrict__ x,
                                                 const float* __restrict__ w0,
                                                 const float* __restrict__ w1,
                                                 const float* __restrict__ wf,
                                                 float* __restrict__ out) {
  const int tid = threadIdx.x;
  const int wid = tid >> 6;         // wave 0..3 -> i offset within group
  const int lane = tid & 63;
  const int g = lane >> 4;          // 0..3 (k-group)
  const int r = lane & 15;          // batch-row / n / j slot
  const int ig = blockIdx.x & 255;  // i-group (4 i's)
  const int bs = blockIdx.x >> 8;   // batch split 0..7 (512 rows each)
  const int i = ig * 4 + wid;
  const int bbase = bs * 512;

  // A1 = w1^T fragment: [row=n=r][k=4g+ii] = w1[i][4g+ii][r]
  half4 aw1;
  {
    const float* w1p = w1 + i * 256 + g * 64 + r;
#pragma unroll
    for (int ii = 0; ii < 4; ++ii) aw1[ii] = (_Float16)w1p[ii * 16];
  }
  // A2 = wf^T fragment: [row=j=r][k2=4g+ii] = wf[i][4g+ii][r], zero for r>=8
  half4 awf;
  {
    const float* wfp = wf + i * 128 + g * 32 + r;
#pragma unroll
    for (int ii = 0; ii < 4; ++ii)
      awf[ii] = (r < 8) ? (_Float16)wfp[ii * 8] : (_Float16)0.0f;
  }
  float w0g[4];
  {
    const float4 v = *(const float4*)(w0 + i * 16 + g * 4);
    w0g[0] = v.x; w0g[1] = v.y; w0g[2] = v.z; w0g[3] = v.w;
  }

  // lane r reads batch row bbase + t*16 + r, column i (broadcast across g)
  const float* xp = x + (size_t)(bbase + r) * 1024 + i;
  float* op = out + (size_t)(bbase + r) * 8192 + i * 8 + g * 4;

  const f32x4 zero = {0.f, 0.f, 0.f, 0.f};
  const bool do_store = (g < 2);

  float xv = xp[0];
#pragma unroll 2
  for (int t = 0; t < 32; ++t) {
    // h1^T fragment (B1): [k=4g+ii][m=r] = tanh(x * w0[i][4g+ii])
    half4 bh1;
#pragma unroll
    for (int ii = 0; ii < 4; ++ii) bh1[ii] = (_Float16)fast_tanh(xv * w0g[ii]);
    // prefetch next tile's x early (16 rows ahead)
    if (t < 31) xv = xp[(size_t)(t + 1) * 16 * 1024];

    // D1[n=4g+ii][m=r] = w1^T @ h1^T
    f32x4 d1 = __builtin_amdgcn_mfma_f32_16x16x16f16(aw1, bh1, zero, 0, 0, 0);
    // h2^T (B2) = tanh(D1) in-register, layout already matches B operand
    half4 bh2;
#pragma unroll
    for (int ii = 0; ii < 4; ++ii) bh2[ii] = (_Float16)fast_tanh(d1[ii]);
    // D2[j=4g+ii][m=r] = wf^T @ h2^T (valid j<8 -> g<2)
    f32x4 d2 = __builtin_amdgcn_mfma_f32_16x16x16f16(awf, bh2, zero, 0, 0, 0);

    if (do_store) *(f32x4*)(op + (size_t)t * 16 * 8192) = d2;
  }
}

extern "C" void kernel_launch(void* const* d_in, const int* in_sizes, int n_in,
                              void* d_out, int out_size, void* d_ws, size_t ws_size,
                              hipStream_t stream) {
  const float* x = (const float*)d_in[0];
  const float* w0 = (const float*)d_in[1];
  const float* w1 = (const float*)d_in[2];
  const float* wf = (const float*)d_in[3];
  float* out = (float*)d_out;
  (void)d_ws; (void)ws_size;
  mlp_fused<<<2048, 256, 0, stream>>>(x, w0, w1, wf, out);
}

// Round 3
// 181.896 us; speedup vs baseline: 1.1572x; 1.1572x over previous
//
#include <hip/hip_runtime.h>

// IndependentMLP: x(4096,1024), w0(1024,1,16), w1(1024,16,16), wf(1024,16,8)
// out[b,i,j] = sum_k tanh( sum_l tanh(x[b,i]*w0[i,l]) * w1[i,l,k] ) * wf[i,k,j]
//
// R2 -> R3 change: R2 was latency-bound (VALUBusy 30%, 2.26 TB/s, 95us) with
// 4x x-fetch amplification (FETCH 68MB vs 16MB ideal). Now each WAVE owns 4
// consecutive i's (one float4 x-load per lane feeds 4 MFMA-pairs = ~160 VALU),
// and the block's 4 waves cover 16 consecutive i's so the 4 waves together
// consume each 64B x-line fully via L1. Prefetch depth 2 covers HBM latency.
//
// Transposed tiny-GEMM trick (verified R1/R2, absmax 0.0625):
//   MFMA1: A = w1^T frag, B = h1^T frag  -> D1[n=h2idx][m=batch]
//   D1's C/D layout == MFMA2's B layout -> tanh in-register, no shuffle.
//   MFMA2: A = wf^T frag, B = tanh(D1)   -> D2[j=outcol][m=batch]
// D2 regs (g<2) = out[b0+r][i*8+g*4 ..+3] -> one aligned float4 store/lane;
// i and i+1 stores fill alternate 32B halves of each 64B line (L2 combines).

typedef _Float16 half4 __attribute__((ext_vector_type(4)));
typedef float f32x4 __attribute__((ext_vector_type(4)));

__device__ __forceinline__ float fast_tanh(float x) {
  // tanh(x) = 1 - 2/(exp2(2x*log2e)+1); +-inf/0 endpoints correct.
  float e = __builtin_amdgcn_exp2f(x * 2.885390081777927f);
  return 1.0f - 2.0f * __builtin_amdgcn_rcpf(e + 1.0f);
}

__global__ __launch_bounds__(256) void mlp_fused(const float* __restrict__ x,
                                                 const float* __restrict__ w0,
                                                 const float* __restrict__ w1,
                                                 const float* __restrict__ wf,
                                                 float* __restrict__ out) {
  const int tid = threadIdx.x;
  const int wid = tid >> 6;         // wave 0..3
  const int lane = tid & 63;
  const int g = lane >> 4;          // 0..3 (k-group)
  const int r = lane & 15;          // batch-row / n / j slot
  const int ig = blockIdx.x & 63;   // i-group of 16 (64 groups)
  const int bs = blockIdx.x >> 6;   // batch split 0..15 (256 rows each)
  const int i0 = ig * 16 + wid * 4; // this wave's 4 i's
  const int bbase = bs * 256;

  // Per-i weight fragments for 4 i's (registers are cheap: R2 used only 16 VGPRs)
  half4 aw1[4];   // A1 = w1^T: [row=n=r][k=4g+kk] = w1[i][4g+kk][r]
  half4 awf[4];   // A2 = wf^T: [row=j=r][k2=4g+kk] = wf[i][4g+kk][r], 0 for r>=8
  f32x4 w0v[4];   // w0[i][4g..4g+3]
#pragma unroll
  for (int ii = 0; ii < 4; ++ii) {
    const int i = i0 + ii;
    const float* w1p = w1 + i * 256 + g * 64 + r;
#pragma unroll
    for (int k = 0; k < 4; ++k) aw1[ii][k] = (_Float16)w1p[k * 16];
    const float* wfp = wf + i * 128 + g * 32 + r;
#pragma unroll
    for (int k = 0; k < 4; ++k)
      awf[ii][k] = (r < 8) ? (_Float16)wfp[k * 8] : (_Float16)0.0f;
    w0v[ii] = *(const f32x4*)(w0 + i * 16 + g * 4);
  }

  // lane r: float4 covering x[b][i0..i0+3]; g-groups broadcast same address.
  const float* xp = x + (size_t)(bbase + r) * 1024 + i0;
  float* op = out + (size_t)(bbase + r) * 8192 + i0 * 8 + g * 4;

  const f32x4 zero = {0.f, 0.f, 0.f, 0.f};
  const bool do_store = (g < 2);

  // software pipeline depth 2: load t+2 while computing t
  f32x4 xa = *(const f32x4*)(xp);
  f32x4 xb = *(const f32x4*)(xp + 16 * 1024);

  for (int t = 0; t < 16; ++t) {
    const int tn = (t + 2 < 16) ? t + 2 : 15;  // clamped prefetch (uniform)
    f32x4 xn = *(const f32x4*)(xp + (size_t)tn * 16 * 1024);

#pragma unroll
    for (int ii = 0; ii < 4; ++ii) {
      // h1^T (B1): [k=4g+kk][m=r] = tanh(x[b0+r][i] * w0[i][4g+kk])
      half4 bh1;
#pragma unroll
      for (int k = 0; k < 4; ++k)
        bh1[k] = (_Float16)fast_tanh(xa[ii] * w0v[ii][k]);
      // D1[n=4g+kk][m=r] = w1^T @ h1^T
      f32x4 d1 = __builtin_amdgcn_mfma_f32_16x16x16f16(aw1[ii], bh1, zero, 0, 0, 0);
      // h2^T (B2) = tanh(D1), layout already matches B operand
      half4 bh2;
#pragma unroll
      for (int k = 0; k < 4; ++k) bh2[k] = (_Float16)fast_tanh(d1[k]);
      // D2[j=4g+kk][m=r] = wf^T @ h2^T (valid j<8 -> g<2)
      f32x4 d2 = __builtin_amdgcn_mfma_f32_16x16x16f16(awf[ii], bh2, zero, 0, 0, 0);
      if (do_store)
        *(f32x4*)(op + (size_t)t * 16 * 8192 + ii * 8) = d2;
    }
    xa = xb;
    xb = xn;
  }
}

extern "C" void kernel_launch(void* const* d_in, const int* in_sizes, int n_in,
                              void* d_out, int out_size, void* d_ws, size_t ws_size,
                              hipStream_t stream) {
  const float* x = (const float*)d_in[0];
  const float* w0 = (const float*)d_in[1];
  const float* w1 = (const float*)d_in[2];
  const float* wf = (const float*)d_in[3];
  float* out = (float*)d_out;
  (void)d_ws; (void)ws_size;
  mlp_fused<<<1024, 256, 0, stream>>>(x, w0, w1, wf, out);
}